// Round 9
// baseline (953.169 us; speedup 1.0000x reference)
//
#include <hip/hip_runtime.h>
#include <hip/hip_bf16.h>
#include <stdint.h>

#define NPTS 500000
#define HSIZE (1u << 20)
#define HMASK (HSIZE - 1)
#define FP 72   // sH row pitch in ushorts: 144B rows -> 16B-aligned b128 reads
#define FPF 68  // sF row pitch in floats: 272B rows -> float4-aligned reads

typedef __attribute__((ext_vector_type(8))) short short8;
typedef __attribute__((ext_vector_type(4))) float float4v;
typedef __attribute__((ext_vector_type(4))) int intx4;

__device__ __forceinline__ unsigned short f2b(float f) {
    __hip_bfloat16 h = __float2bfloat16(f);
    return __builtin_bit_cast(unsigned short, h);
}
__device__ __forceinline__ float b2f(unsigned short u) {
    return __builtin_bit_cast(float, ((unsigned)u) << 16);
}

// ---- convert W1, W2 (f32, [s][c][j]) to bf16 transposed [s][j][c]; zero gctr ----
__global__ __launch_bounds__(256) void wconv(const float* __restrict__ W1,
                                             const float* __restrict__ W2,
                                             unsigned short* __restrict__ W1T,
                                             unsigned short* __restrict__ W2T,
                                             int* __restrict__ gctr) {
    int i = blockIdx.x * 256 + threadIdx.x;
    if (i < 192) gctr[i] = 0;
    if (i >= 3 * 4096) return;
    int s = i >> 12, rem = i & 4095, c = rem >> 6, j = rem & 63;
    W1T[s * 4096 + j * 64 + c] = f2b(W1[i]);
    W2T[s * 4096 + j * 64 + c] = f2b(W2[i]);
}

// ---- all 3 scales: 64-bit (key,gid) hash insert + per-slot chain + compact slot list ----
__global__ __launch_bounds__(256) void insert3(const int* __restrict__ coords,
                                               unsigned long long* __restrict__ hKV,
                                               int* __restrict__ head,
                                               int* __restrict__ next,
                                               int* __restrict__ cslot,
                                               int* __restrict__ gctr) {
    const int BPS = (NPTS + 255) / 256;  // 1954
    int s = blockIdx.x / BPS;
    int i = (blockIdx.x % BPS) * 256 + threadIdx.x;
    int shift = s + 1;
    unsigned long long* hs = hKV + (size_t)s * HSIZE;
    int* heads = head + (size_t)s * HSIZE;
    int* nexts = next + (size_t)s * NPTS;
    bool active = i < NPTS;
    unsigned h = 0;
    bool inserted = false;
    if (active) {
        int4 cd = ((const int4*)coords)[i];
        int key = (((cd.w * 512 + (cd.x >> shift)) * 512 + (cd.y >> shift)) * 512 +
                   (cd.z >> shift));
        unsigned long long want = (unsigned long long)(unsigned)key | 0xFFFFFFFF00000000ull;
        h = ((unsigned)key * 2654435761u) >> 12;  // top 20 bits
        while (true) {
            unsigned long long prev = atomicCAS(&hs[h], ~0ull, want);
            if (prev == ~0ull) { inserted = true; break; }
            if ((int)(prev & 0xFFFFFFFFull) == key) break;
            h = (h + 1) & HMASK;
        }
        nexts[i] = atomicExch(&heads[h], i);
    }
    unsigned long long mask = __ballot(inserted);
    if (mask) {
        int lane = threadIdx.x & 63;
        int leader = __ffsll((unsigned long long)mask) - 1;
        int base = 0;
        if (lane == leader) base = atomicAdd(&gctr[s * 64], __popcll(mask));
        base = __shfl(base, leader);
        if (inserted) {
            int gid = base + __popcll(mask & ((1ull << lane) - 1ull));
            ((int*)&hs[h])[1] = gid;  // high word; slot can never be CAS'd again
            cslot[(size_t)s * NPTS + gid] = (int)h;
        }
    }
}

// ---- resolve chain heads into a dense gid-indexed array ----
__global__ __launch_bounds__(256) void headfix3(const int* __restrict__ cslot,
                                                const int* __restrict__ head,
                                                const int* __restrict__ gctr,
                                                int* __restrict__ chead) {
    int t = blockIdx.x * 256 + threadIdx.x;
    int s = t / NPTS;
    if (s >= 3) return;
    int gid = t - s * NPTS;
    if (gid >= gctr[s * 64]) return;
    chead[(size_t)s * NPTS + gid] =
        head[(size_t)s * HSIZE + cslot[(size_t)s * NPTS + gid]];
}

// ---- all 3 scales: 16 lanes per group, float4/lane, walk chain, exact mean -> bf16 ----
__global__ __launch_bounds__(256) void reduce3(const float4* __restrict__ feats4,
                                               const int* __restrict__ chead,
                                               const int* __restrict__ next,
                                               const int* __restrict__ gctr,
                                               ushort4* __restrict__ vmean4) {
    int t = blockIdx.x * 256 + threadIdx.x;
    int sub = t >> 4;   // group index over 3*NPTS
    int sl = t & 15;    // sublane: 16 x float4 = 64 channels
    int s = sub / NPTS;
    if (s >= 3) return;
    int gid = sub - s * NPTS;
    if (gid >= gctr[s * 64]) return;
    int i = chead[(size_t)s * NPTS + gid];  // dense coalesced load
    const int* nexts = next + (size_t)s * NPTS;
    float4 sum = {0.f, 0.f, 0.f, 0.f};
    int cnt = 0;
    while (i >= 0) {
        float4 v = feats4[(size_t)i * 16 + sl];  // 256B coalesced row
        int ni = nexts[i];                       // independent of v
        sum.x += v.x; sum.y += v.y; sum.z += v.z; sum.w += v.w;
        cnt++;
        i = ni;
    }
    float cf = (float)cnt;
    ushort4 o;
    o.x = f2b(sum.x / cf);
    o.y = f2b(sum.y / cf);
    o.z = f2b(sum.z / cf);
    o.w = f2b(sum.w / cf);
    vmean4[((size_t)s * NPTS + gid) * 16 + sl] = o;
}

// ---- fused: inline corner-argmax + gather vmean + 3x MLP + attention ----
// Cache-policy isolation (R6 lesson): feats/coords/out are zero-reuse streams ->
// nontemporal (no LLC allocate). hKV (24 MB) + vmean (183 MB) then fit the 256 MB
// L3 together, so the 12M hash probes and the vmean gathers stay LLC-hit.
__global__ __launch_bounds__(256, 4) void fused_mlp(const float* __restrict__ feats,
                                                    const int* __restrict__ coords,
                                                    const int2* __restrict__ hKV,
                                                    const unsigned short* __restrict__ vmean,
                                                    const unsigned short* __restrict__ W1T,
                                                    const unsigned short* __restrict__ W2T,
                                                    const float* __restrict__ b1,
                                                    const float* __restrict__ b2,
                                                    const float* __restrict__ Wa,
                                                    const float* __restrict__ ba,
                                                    float* __restrict__ out) {
    __shared__ __align__(16) float sF[64 * FPF];              // 17408 B
    __shared__ __align__(16) unsigned short sH[4][16 * FP];   // 9216 B
    __shared__ int sG[3][64];                                 // 768 B

    int tid = threadIdx.x;
    int wave = tid >> 6, lane = tid & 63;
    int ln = lane & 15, quad = lane >> 4, ko = quad * 8;
    int b0 = blockIdx.x * 64;
    int mrow = wave * 16 + ln;

    // cooperative feats tile fill: 16 floats per thread, coalesced, NON-TEMPORAL
    int frow = tid >> 2, fcb = (tid & 3) * 16;
    {
        int n = b0 + frow;
        const float4v* src = (const float4v*)(feats + (size_t)(n < NPTS ? n : 0) * 64 + fcb);
        float4v z = {0.f, 0.f, 0.f, 0.f};
#pragma unroll
        for (int k = 0; k < 4; ++k) {
            float4v v = (n < NPTS) ? __builtin_nontemporal_load(src + k) : z;
            *(float4v*)&sF[frow * FPF + fcb + 4 * k] = v;
        }
    }

    // ---- inline argmax: row = tid>>2, this thread owns corners cc and cc+4 ----
    {
        int row = tid >> 2, cc = tid & 3;
        int n = b0 + row;
        bool act = n < NPTS;
        intx4 cd = {0, 0, 0, 0};
        if (act) cd = __builtin_nontemporal_load((const intx4*)coords + n);
#pragma unroll
        for (int s = 0; s < 3; ++s) {
            int wj = 0, wg = 0;
            if (act) {
                int shift = s + 1;
                const int2* hs = hKV + (size_t)s * HSIZE;
                int vx = cd.x >> shift, vy = cd.y >> shift, vz = cd.z >> shift;
                float inv = 1.0f / (float)(1 << shift);
                float fx = (float)(cd.x - (vx << shift)) * inv;  // exact dyadic
                float fy = (float)(cd.y - (vy << shift)) * inv;
                float fz = (float)(cd.z - (vz << shift)) * inv;
                float wb = -1.0f;
                int jb = 0, gb = 0;
#pragma unroll
                for (int k = 0; k < 2; ++k) {
                    int j = cc + k * 4;
                    int bx = (j >> 2) & 1, by = (j >> 1) & 1, bz = j & 1;
                    float wx = bx ? fx : 1.0f - fx;
                    float wy = by ? fy : 1.0f - fy;
                    float wz = bz ? fz : 1.0f - fz;
                    float w = (wx * wy) * wz;  // same assoc order as jnp.prod
                    int key = (((cd.w * 512 + (vx + bx)) * 512 + (vy + by)) * 512 + (vz + bz));
                    unsigned h = ((unsigned)key * 2654435761u) >> 12;
                    int g = -1;
                    while (true) {
                        int2 kv = hs[h];   // cacheable: hKV must stay L3-resident
                        if (kv.x == key) { g = kv.y; break; }
                        if (kv.x == -1) break;
                        h = (h + 1) & HMASK;
                    }
                    if (g < 0) w = 0.0f;
                    // local first-max: strict greater (tie keeps earlier j; j < j+4)
                    if (w > wb) { wb = w; jb = j; gb = g; }
                }
                // cross-lane reduce over the 4-lane row group (xor 1,2 stay in group)
                float w = wb; wj = jb; wg = gb;
#pragma unroll
                for (int m = 1; m < 4; m <<= 1) {
                    float ow = __shfl_xor(w, m);
                    int oj = __shfl_xor(wj, m);
                    int og = __shfl_xor(wg, m);
                    if (ow > w || (ow == w && oj < wj)) { w = ow; wj = oj; wg = og; }
                }
                if (wg < 0) wg = 0;  // unreachable (corner 0 always found), safety
            }
            if (cc == 0) sG[s][row] = wg;
        }
    }

    __syncthreads();  // sF fill + sG ready

    // gather gids (LDS broadcast) + 6 independent vmean gathers in flight (cacheable)
    int gg[3];
#pragma unroll
    for (int s = 0; s < 3; ++s) gg[s] = sG[s][mrow];
    short8 u0v[3], u1v[3];
#pragma unroll
    for (int s = 0; s < 3; ++s) {
        const unsigned short* vr = vmean + ((size_t)s * NPTS + gg[s]) * 64;
        u0v[s] = *(const short8*)&vr[ko];
        u1v[s] = *(const short8*)&vr[32 + ko];
    }

    float4v ms[3][4];
    unsigned short* sHw = &sH[wave][0];
    unsigned zo = 0;  // runtime-0, laundered per scale (defeats cross-scale CSE)

#pragma unroll
    for (int s = 0; s < 3; ++s) {
        asm volatile("" : "+v"(zo));

        // residual A-fragments: res = feats - vmean[gid]  (feats via float4 LDS reads)
        short8 u0 = u0v[s], u1 = u1v[s];
        float fa0[8], fa1[8];
        *(float4v*)&fa0[0] = *(const float4v*)&sF[zo + mrow * FPF + ko];
        *(float4v*)&fa0[4] = *(const float4v*)&sF[zo + mrow * FPF + ko + 4];
        *(float4v*)&fa1[0] = *(const float4v*)&sF[zo + mrow * FPF + 32 + ko];
        *(float4v*)&fa1[4] = *(const float4v*)&sF[zo + mrow * FPF + 32 + ko + 4];
        short8 a0, a1;
#pragma unroll
        for (int j = 0; j < 8; ++j) {
            a0[j] = (short)f2b(fa0[j] - b2f((unsigned short)u0[j]));
            a1[j] = (short)f2b(fa1[j] - b2f((unsigned short)u1[j]));
        }

        // GEMM1: H = relu(res @ W1 + b1) * feats
#pragma unroll
        for (int nt = 0; nt < 4; ++nt) {
            int ncol = nt * 16 + ln;
            const unsigned short* w1r = W1T + s * 4096 + ncol * 64;
            short8 bb0 = *(const short8*)&w1r[ko];
            short8 bb1 = *(const short8*)&w1r[32 + ko];
            float4v c = {0.f, 0.f, 0.f, 0.f};
            c = __builtin_amdgcn_mfma_f32_16x16x32_bf16(a0, bb0, c, 0, 0, 0);
            c = __builtin_amdgcn_mfma_f32_16x16x32_bf16(a1, bb1, c, 0, 0, 0);
            float bias = b1[s * 64 + ncol];
#pragma unroll
            for (int r = 0; r < 4; ++r) {
                float fcv = sF[zo + (wave * 16 + quad * 4 + r) * FPF + ncol];
                float hv = fmaxf(c[r] + bias, 0.0f) * fcv;
                sHw[(quad * 4 + r) * FP + ncol] = f2b(hv);
            }
        }
        // (no fence: sH is wave-private; compiler orders aliasing LDS write->read)

        // GEMM2: ms = relu(H @ W2 + b2)
        short8 h0 = *(const short8*)&sHw[ln * FP + ko];
        short8 h1 = *(const short8*)&sHw[ln * FP + 32 + ko];
#pragma unroll
        for (int nt = 0; nt < 4; ++nt) {
            int ncol = nt * 16 + ln;
            const unsigned short* w2r = W2T + s * 4096 + ncol * 64;
            short8 bb0 = *(const short8*)&w2r[ko];
            short8 bb1 = *(const short8*)&w2r[32 + ko];
            float4v c = {0.f, 0.f, 0.f, 0.f};
            c = __builtin_amdgcn_mfma_f32_16x16x32_bf16(h0, bb0, c, 0, 0, 0);
            c = __builtin_amdgcn_mfma_f32_16x16x32_bf16(h1, bb1, c, 0, 0, 0);
            float bias2 = b2[s * 64 + ncol];
#pragma unroll
            for (int r = 0; r < 4; ++r) c[r] = fmaxf(c[r] + bias2, 0.0f);
            ms[s][nt] = c;
        }
    }

    // attention: att = sigmoid((ms0+ms1+ms2) @ Wa^T + ba); out = sum_s ms_s * att_s
    float4v sa[4];
#pragma unroll
    for (int nt = 0; nt < 4; ++nt) sa[nt] = ms[0][nt] + ms[1][nt] + ms[2][nt];
    float part[4][3];
#pragma unroll
    for (int r = 0; r < 4; ++r)
#pragma unroll
        for (int sh = 0; sh < 3; ++sh) {
            float p = 0.0f;
#pragma unroll
            for (int nt = 0; nt < 4; ++nt) p += sa[nt][r] * Wa[sh * 64 + nt * 16 + ln];
            part[r][sh] = p;
        }
    for (int m = 1; m < 16; m <<= 1)
#pragma unroll
        for (int r = 0; r < 4; ++r)
#pragma unroll
            for (int sh = 0; sh < 3; ++sh) part[r][sh] += __shfl_xor(part[r][sh], m);
    float att[4][3];
#pragma unroll
    for (int r = 0; r < 4; ++r)
#pragma unroll
        for (int sh = 0; sh < 3; ++sh)
            att[r][sh] = 1.0f / (1.0f + expf(-(part[r][sh] + ba[sh])));

#pragma unroll
    for (int nt = 0; nt < 4; ++nt)
#pragma unroll
        for (int r = 0; r < 4; ++r) {
            int n = b0 + wave * 16 + quad * 4 + r;
            if (n < NPTS) {
                float o = ms[0][nt][r] * att[r][0] + ms[1][nt][r] * att[r][1] +
                          ms[2][nt][r] * att[r][2];
                __builtin_nontemporal_store(o, &out[(size_t)n * 64 + nt * 16 + ln]);
            }
        }
}

extern "C" void kernel_launch(void* const* d_in, const int* in_sizes, int n_in,
                              void* d_out, int out_size, void* d_ws, size_t ws_size,
                              hipStream_t stream) {
    const float* feats = (const float*)d_in[0];
    const int* coords = (const int*)d_in[1];
    const float* W1 = (const float*)d_in[2];
    const float* b1 = (const float*)d_in[3];
    const float* W2 = (const float*)d_in[4];
    const float* b2 = (const float*)d_in[5];
    const float* Wa = (const float*)d_in[6];
    const float* ba = (const float*)d_in[7];
    float* out = (float*)d_out;

    char* ws = (char*)d_ws;
    size_t o = 0;
    unsigned short* W1T = (unsigned short*)(ws + o); o += 3 * 4096 * 2;
    unsigned short* W2T = (unsigned short*)(ws + o); o += 3 * 4096 * 2;
    o = (o + 255) & ~(size_t)255;
    unsigned short* vmean = (unsigned short*)(ws + o); o += (size_t)3 * NPTS * 64 * 2;
    int* next = (int*)(ws + o); o += (size_t)3 * NPTS * 4;
    int* cslot = (int*)(ws + o); o += (size_t)3 * NPTS * 4;
    int* chead = (int*)(ws + o); o += (size_t)3 * NPTS * 4;
    o = (o + 255) & ~(size_t)255;
    unsigned long long* hKV = (unsigned long long*)(ws + o); o += (size_t)3 * HSIZE * 8;
    int* head = (int*)(ws + o); o += (size_t)3 * HSIZE * 4;  // contiguous with hKV
    int* gctr = (int*)(ws + o); o += 192 * 4;
    // total ~247 MB

    wconv<<<48, 256, 0, stream>>>(W1, W2, W1T, W2T, gctr);
    (void)hipMemsetAsync(hKV, 0xFF, (size_t)3 * HSIZE * 12, stream);  // hKV + head in one memset

    const int BPS = (NPTS + 255) / 256;
    insert3<<<3 * BPS, 256, 0, stream>>>(coords, hKV, head, next, cslot, gctr);
    headfix3<<<(3 * NPTS + 255) / 256, 256, 0, stream>>>(cslot, head, gctr, chead);
    reduce3<<<(3 * NPTS * 16 + 255) / 256, 256, 0, stream>>>((const float4*)feats, chead,
                                                             next, gctr, (ushort4*)vmean);
    fused_mlp<<<(NPTS + 63) / 64, 256, 0, stream>>>(feats, coords, (const int2*)hKV, vmean,
                                                    W1T, W2T, b1, b2, Wa, ba, out);
}

// Round 10
// 862.059 us; speedup vs baseline: 1.1057x; 1.1057x over previous
//
#include <hip/hip_runtime.h>
#include <hip/hip_bf16.h>
#include <stdint.h>

#define NPTS 500000
#define HSIZE (1u << 20)
#define HMASK (HSIZE - 1)
#define FP 72   // sH row pitch in ushorts: 144B rows -> 16B-aligned b128 reads
#define FPF 68  // sF row pitch in floats: 272B rows -> float4-aligned reads

typedef __attribute__((ext_vector_type(8))) short short8;
typedef __attribute__((ext_vector_type(4))) float float4v;
typedef __attribute__((ext_vector_type(4))) int intx4;

__device__ __forceinline__ unsigned short f2b(float f) {
    __hip_bfloat16 h = __float2bfloat16(f);
    return __builtin_bit_cast(unsigned short, h);
}
__device__ __forceinline__ float b2f(unsigned short u) {
    return __builtin_bit_cast(float, ((unsigned)u) << 16);
}

// ---- convert W1, W2 (f32, [s][c][j]) to bf16 transposed [s][j][c]; zero gctr ----
__global__ __launch_bounds__(256) void wconv(const float* __restrict__ W1,
                                             const float* __restrict__ W2,
                                             unsigned short* __restrict__ W1T,
                                             unsigned short* __restrict__ W2T,
                                             int* __restrict__ gctr) {
    int i = blockIdx.x * 256 + threadIdx.x;
    if (i < 192) gctr[i] = 0;
    if (i >= 3 * 4096) return;
    int s = i >> 12, rem = i & 4095, c = rem >> 6, j = rem & 63;
    W1T[s * 4096 + j * 64 + c] = f2b(W1[i]);
    W2T[s * 4096 + j * 64 + c] = f2b(W2[i]);
}

// ---- all 3 scales: 64-bit (key,gid) hash insert + per-slot chain + compact slot list ----
__global__ __launch_bounds__(256) void insert3(const int* __restrict__ coords,
                                               unsigned long long* __restrict__ hKV,
                                               int* __restrict__ head,
                                               int* __restrict__ next,
                                               int* __restrict__ cslot,
                                               int* __restrict__ gctr) {
    const int BPS = (NPTS + 255) / 256;  // 1954
    int s = blockIdx.x / BPS;
    int i = (blockIdx.x % BPS) * 256 + threadIdx.x;
    int shift = s + 1;
    unsigned long long* hs = hKV + (size_t)s * HSIZE;
    int* heads = head + (size_t)s * HSIZE;
    int* nexts = next + (size_t)s * NPTS;
    bool active = i < NPTS;
    unsigned h = 0;
    bool inserted = false;
    if (active) {
        int4 cd = ((const int4*)coords)[i];
        int key = (((cd.w * 512 + (cd.x >> shift)) * 512 + (cd.y >> shift)) * 512 +
                   (cd.z >> shift));
        unsigned long long want = (unsigned long long)(unsigned)key | 0xFFFFFFFF00000000ull;
        h = ((unsigned)key * 2654435761u) >> 12;  // top 20 bits
        while (true) {
            unsigned long long prev = atomicCAS(&hs[h], ~0ull, want);
            if (prev == ~0ull) { inserted = true; break; }
            if ((int)(prev & 0xFFFFFFFFull) == key) break;
            h = (h + 1) & HMASK;
        }
        nexts[i] = atomicExch(&heads[h], i);
    }
    unsigned long long mask = __ballot(inserted);
    if (mask) {
        int lane = threadIdx.x & 63;
        int leader = __ffsll((unsigned long long)mask) - 1;
        int base = 0;
        if (lane == leader) base = atomicAdd(&gctr[s * 64], __popcll(mask));
        base = __shfl(base, leader);
        if (inserted) {
            int gid = base + __popcll(mask & ((1ull << lane) - 1ull));
            ((int*)&hs[h])[1] = gid;  // high word; slot can never be CAS'd again
            cslot[(size_t)s * NPTS + gid] = (int)h;
        }
    }
}

// ---- resolve chain heads into a dense gid-indexed array ----
__global__ __launch_bounds__(256) void headfix3(const int* __restrict__ cslot,
                                                const int* __restrict__ head,
                                                const int* __restrict__ gctr,
                                                int* __restrict__ chead) {
    int t = blockIdx.x * 256 + threadIdx.x;
    int s = t / NPTS;
    if (s >= 3) return;
    int gid = t - s * NPTS;
    if (gid >= gctr[s * 64]) return;
    chead[(size_t)s * NPTS + gid] =
        head[(size_t)s * HSIZE + cslot[(size_t)s * NPTS + gid]];
}

// ---- all 3 scales: 16 lanes per group, float4/lane, walk chain, exact mean -> bf16 ----
__global__ __launch_bounds__(256) void reduce3(const float4* __restrict__ feats4,
                                               const int* __restrict__ chead,
                                               const int* __restrict__ next,
                                               const int* __restrict__ gctr,
                                               ushort4* __restrict__ vmean4) {
    int t = blockIdx.x * 256 + threadIdx.x;
    int sub = t >> 4;   // group index over 3*NPTS
    int sl = t & 15;    // sublane: 16 x float4 = 64 channels
    int s = sub / NPTS;
    if (s >= 3) return;
    int gid = sub - s * NPTS;
    if (gid >= gctr[s * 64]) return;
    int i = chead[(size_t)s * NPTS + gid];  // dense coalesced load
    const int* nexts = next + (size_t)s * NPTS;
    float4 sum = {0.f, 0.f, 0.f, 0.f};
    int cnt = 0;
    while (i >= 0) {
        float4 v = feats4[(size_t)i * 16 + sl];  // 256B coalesced row
        int ni = nexts[i];                       // independent of v
        sum.x += v.x; sum.y += v.y; sum.z += v.z; sum.w += v.w;
        cnt++;
        i = ni;
    }
    float cf = (float)cnt;
    ushort4 o;
    o.x = f2b(sum.x / cf);
    o.y = f2b(sum.y / cf);
    o.z = f2b(sum.z / cf);
    o.w = f2b(sum.w / cf);
    vmean4[((size_t)s * NPTS + gid) * 16 + sl] = o;
}

// ---- fused: pruned corner-argmax + gather vmean + 3x MLP + attention ----
// Probe pruning (R9 lesson: nt hints don't protect L3; cut probe COUNT instead):
// corner weights are probe-free arithmetic; corner0 (own voxel) is always occupied
// with w0>0. Scan corners in (w desc, j asc) order, stop at first OCCUPIED ->
// provably identical to reference first-max argmax. ~2.8M probes vs 12M.
// Threads 0..191 = (scale s = tid>>6, row = tid&63), one early-exit scan each.
__global__ __launch_bounds__(256, 4) void fused_mlp(const float* __restrict__ feats,
                                                    const int* __restrict__ coords,
                                                    const int2* __restrict__ hKV,
                                                    const unsigned short* __restrict__ vmean,
                                                    const unsigned short* __restrict__ W1T,
                                                    const unsigned short* __restrict__ W2T,
                                                    const float* __restrict__ b1,
                                                    const float* __restrict__ b2,
                                                    const float* __restrict__ Wa,
                                                    const float* __restrict__ ba,
                                                    float* __restrict__ out) {
    __shared__ __align__(16) float sF[64 * FPF];              // 17408 B
    __shared__ __align__(16) unsigned short sH[4][16 * FP];   // 9216 B
    __shared__ int sG[3][64];                                 // 768 B

    int tid = threadIdx.x;
    int wave = tid >> 6, lane = tid & 63;
    int ln = lane & 15, quad = lane >> 4, ko = quad * 8;
    int b0 = blockIdx.x * 64;
    int mrow = wave * 16 + ln;

    // cooperative feats tile fill: 16 floats per thread, coalesced
    int frow = tid >> 2, fcb = (tid & 3) * 16;
    {
        int n = b0 + frow;
        const float4v* src = (const float4v*)(feats + (size_t)(n < NPTS ? n : 0) * 64 + fcb);
        float4v z = {0.f, 0.f, 0.f, 0.f};
#pragma unroll
        for (int k = 0; k < 4; ++k) {
            float4v v = (n < NPTS) ? src[k] : z;
            *(float4v*)&sF[frow * FPF + fcb + 4 * k] = v;
        }
    }

    // ---- pruned argmax: thread (s,row) scans corners best-weight-first ----
    if (tid < 192) {
        int row = tid & 63, s = tid >> 6;
        int n = b0 + row;
        int wg = 0;
        if (n < NPTS) {
            intx4 cd = *((const intx4*)coords + n);
            int shift = s + 1;
            const int2* hs = hKV + (size_t)s * HSIZE;
            int vx = cd.x >> shift, vy = cd.y >> shift, vz = cd.z >> shift;
            float inv = 1.0f / (float)(1 << shift);
            float fx = (float)(cd.x - (vx << shift)) * inv;  // exact dyadic
            float fy = (float)(cd.y - (vy << shift)) * inv;
            float fz = (float)(cd.z - (vz << shift)) * inv;
            float cw[8];
#pragma unroll
            for (int j = 0; j < 8; ++j) {
                float wx = ((j >> 2) & 1) ? fx : 1.0f - fx;
                float wy = ((j >> 1) & 1) ? fy : 1.0f - fy;
                float wz = (j & 1) ? fz : 1.0f - fz;
                cw[j] = (wx * wy) * wz;  // same assoc order as jnp.prod; exact f32
            }
            unsigned done = 0;
            for (int it = 0; it < 8; ++it) {
                // select max (w, -j) among not-done: strict > keeps smallest j on tie
                int best = 0; float bw = -1.0f;
#pragma unroll
                for (int j = 0; j < 8; ++j)
                    if (!(done & (1u << j)) && cw[j] > bw) { bw = cw[j]; best = j; }
                int bx = (best >> 2) & 1, by = (best >> 1) & 1, bz = best & 1;
                int key = (((cd.w * 512 + (vx + bx)) * 512 + (vy + by)) * 512 + (vz + bz));
                unsigned h = ((unsigned)key * 2654435761u) >> 12;
                int g = -1;
                while (true) {
                    int2 kv = hs[h];
                    if (kv.x == key) { g = kv.y; break; }
                    if (kv.x == -1) break;
                    h = (h + 1) & HMASK;
                }
                if (g >= 0) { wg = g; break; }  // first occupied in order = argmax
                done |= 1u << best;
                // terminates at latest at corner0 (always occupied, w0 > 0)
            }
        }
        sG[s][row] = wg;
    }

    __syncthreads();  // sF fill + sG ready

    // gather gids (LDS broadcast) + 6 independent vmean gathers in flight
    int gg[3];
#pragma unroll
    for (int s = 0; s < 3; ++s) gg[s] = sG[s][mrow];
    short8 u0v[3], u1v[3];
#pragma unroll
    for (int s = 0; s < 3; ++s) {
        const unsigned short* vr = vmean + ((size_t)s * NPTS + gg[s]) * 64;
        u0v[s] = *(const short8*)&vr[ko];
        u1v[s] = *(const short8*)&vr[32 + ko];
    }

    float4v ms[3][4];
    unsigned short* sHw = &sH[wave][0];
    unsigned zo = 0;  // runtime-0, laundered per scale (defeats cross-scale CSE)

#pragma unroll
    for (int s = 0; s < 3; ++s) {
        asm volatile("" : "+v"(zo));

        // residual A-fragments: res = feats - vmean[gid]  (feats via float4 LDS reads)
        short8 u0 = u0v[s], u1 = u1v[s];
        float fa0[8], fa1[8];
        *(float4v*)&fa0[0] = *(const float4v*)&sF[zo + mrow * FPF + ko];
        *(float4v*)&fa0[4] = *(const float4v*)&sF[zo + mrow * FPF + ko + 4];
        *(float4v*)&fa1[0] = *(const float4v*)&sF[zo + mrow * FPF + 32 + ko];
        *(float4v*)&fa1[4] = *(const float4v*)&sF[zo + mrow * FPF + 32 + ko + 4];
        short8 a0, a1;
#pragma unroll
        for (int j = 0; j < 8; ++j) {
            a0[j] = (short)f2b(fa0[j] - b2f((unsigned short)u0[j]));
            a1[j] = (short)f2b(fa1[j] - b2f((unsigned short)u1[j]));
        }

        // GEMM1: H = relu(res @ W1 + b1) * feats
#pragma unroll
        for (int nt = 0; nt < 4; ++nt) {
            int ncol = nt * 16 + ln;
            const unsigned short* w1r = W1T + s * 4096 + ncol * 64;
            short8 bb0 = *(const short8*)&w1r[ko];
            short8 bb1 = *(const short8*)&w1r[32 + ko];
            float4v c = {0.f, 0.f, 0.f, 0.f};
            c = __builtin_amdgcn_mfma_f32_16x16x32_bf16(a0, bb0, c, 0, 0, 0);
            c = __builtin_amdgcn_mfma_f32_16x16x32_bf16(a1, bb1, c, 0, 0, 0);
            float bias = b1[s * 64 + ncol];
#pragma unroll
            for (int r = 0; r < 4; ++r) {
                float fcv = sF[zo + (wave * 16 + quad * 4 + r) * FPF + ncol];
                float hv = fmaxf(c[r] + bias, 0.0f) * fcv;
                sHw[(quad * 4 + r) * FP + ncol] = f2b(hv);
            }
        }
        // (no fence: sH is wave-private; compiler orders aliasing LDS write->read)

        // GEMM2: ms = relu(H @ W2 + b2)
        short8 h0 = *(const short8*)&sHw[ln * FP + ko];
        short8 h1 = *(const short8*)&sHw[ln * FP + 32 + ko];
#pragma unroll
        for (int nt = 0; nt < 4; ++nt) {
            int ncol = nt * 16 + ln;
            const unsigned short* w2r = W2T + s * 4096 + ncol * 64;
            short8 bb0 = *(const short8*)&w2r[ko];
            short8 bb1 = *(const short8*)&w2r[32 + ko];
            float4v c = {0.f, 0.f, 0.f, 0.f};
            c = __builtin_amdgcn_mfma_f32_16x16x32_bf16(h0, bb0, c, 0, 0, 0);
            c = __builtin_amdgcn_mfma_f32_16x16x32_bf16(h1, bb1, c, 0, 0, 0);
            float bias2 = b2[s * 64 + ncol];
#pragma unroll
            for (int r = 0; r < 4; ++r) c[r] = fmaxf(c[r] + bias2, 0.0f);
            ms[s][nt] = c;
        }
    }

    // attention: att = sigmoid((ms0+ms1+ms2) @ Wa^T + ba); out = sum_s ms_s * att_s
    float4v sa[4];
#pragma unroll
    for (int nt = 0; nt < 4; ++nt) sa[nt] = ms[0][nt] + ms[1][nt] + ms[2][nt];
    float part[4][3];
#pragma unroll
    for (int r = 0; r < 4; ++r)
#pragma unroll
        for (int sh = 0; sh < 3; ++sh) {
            float p = 0.0f;
#pragma unroll
            for (int nt = 0; nt < 4; ++nt) p += sa[nt][r] * Wa[sh * 64 + nt * 16 + ln];
            part[r][sh] = p;
        }
    for (int m = 1; m < 16; m <<= 1)
#pragma unroll
        for (int r = 0; r < 4; ++r)
#pragma unroll
            for (int sh = 0; sh < 3; ++sh) part[r][sh] += __shfl_xor(part[r][sh], m);
    float att[4][3];
#pragma unroll
    for (int r = 0; r < 4; ++r)
#pragma unroll
        for (int sh = 0; sh < 3; ++sh)
            att[r][sh] = 1.0f / (1.0f + expf(-(part[r][sh] + ba[sh])));

#pragma unroll
    for (int nt = 0; nt < 4; ++nt)
#pragma unroll
        for (int r = 0; r < 4; ++r) {
            int n = b0 + wave * 16 + quad * 4 + r;
            if (n < NPTS) {
                float o = ms[0][nt][r] * att[r][0] + ms[1][nt][r] * att[r][1] +
                          ms[2][nt][r] * att[r][2];
                out[(size_t)n * 64 + nt * 16 + ln] = o;
            }
        }
}

extern "C" void kernel_launch(void* const* d_in, const int* in_sizes, int n_in,
                              void* d_out, int out_size, void* d_ws, size_t ws_size,
                              hipStream_t stream) {
    const float* feats = (const float*)d_in[0];
    const int* coords = (const int*)d_in[1];
    const float* W1 = (const float*)d_in[2];
    const float* b1 = (const float*)d_in[3];
    const float* W2 = (const float*)d_in[4];
    const float* b2 = (const float*)d_in[5];
    const float* Wa = (const float*)d_in[6];
    const float* ba = (const float*)d_in[7];
    float* out = (float*)d_out;

    char* ws = (char*)d_ws;
    size_t o = 0;
    unsigned short* W1T = (unsigned short*)(ws + o); o += 3 * 4096 * 2;
    unsigned short* W2T = (unsigned short*)(ws + o); o += 3 * 4096 * 2;
    o = (o + 255) & ~(size_t)255;
    unsigned short* vmean = (unsigned short*)(ws + o); o += (size_t)3 * NPTS * 64 * 2;
    int* next = (int*)(ws + o); o += (size_t)3 * NPTS * 4;
    int* cslot = (int*)(ws + o); o += (size_t)3 * NPTS * 4;
    int* chead = (int*)(ws + o); o += (size_t)3 * NPTS * 4;
    o = (o + 255) & ~(size_t)255;
    unsigned long long* hKV = (unsigned long long*)(ws + o); o += (size_t)3 * HSIZE * 8;
    int* head = (int*)(ws + o); o += (size_t)3 * HSIZE * 4;  // contiguous with hKV
    int* gctr = (int*)(ws + o); o += 192 * 4;
    // total ~247 MB

    wconv<<<48, 256, 0, stream>>>(W1, W2, W1T, W2T, gctr);
    (void)hipMemsetAsync(hKV, 0xFF, (size_t)3 * HSIZE * 12, stream);  // hKV + head in one memset

    const int BPS = (NPTS + 255) / 256;
    insert3<<<3 * BPS, 256, 0, stream>>>(coords, hKV, head, next, cslot, gctr);
    headfix3<<<(3 * NPTS + 255) / 256, 256, 0, stream>>>(cslot, head, gctr, chead);
    reduce3<<<(3 * NPTS * 16 + 255) / 256, 256, 0, stream>>>((const float4*)feats, chead,
                                                             next, gctr, (ushort4*)vmean);
    fused_mlp<<<(NPTS + 63) / 64, 256, 0, stream>>>(feats, coords, (const int2*)hKV, vmean,
                                                    W1T, W2T, b1, b2, Wa, ba, out);
}

// Round 11
// 656.055 us; speedup vs baseline: 1.4529x; 1.3140x over previous
//
#include <hip/hip_runtime.h>
#include <hip/hip_bf16.h>
#include <stdint.h>

#define NPTS 500000
#define HSIZE (1u << 20)
#define HMASK (HSIZE - 1)
#define FP 72   // sH row pitch in ushorts: 144B rows -> 16B-aligned b128 reads
#define FPF 68  // sF row pitch in floats: 272B rows -> float4-aligned reads

typedef __attribute__((ext_vector_type(8))) short short8;
typedef __attribute__((ext_vector_type(4))) float float4v;
typedef __attribute__((ext_vector_type(4))) int intx4;

__device__ __forceinline__ unsigned short f2b(float f) {
    __hip_bfloat16 h = __float2bfloat16(f);
    return __builtin_bit_cast(unsigned short, h);
}
__device__ __forceinline__ float b2f(unsigned short u) {
    return __builtin_bit_cast(float, ((unsigned)u) << 16);
}

// ---- convert W1, W2 (f32, [s][c][j]) to bf16 transposed [s][j][c] ----
__global__ __launch_bounds__(256) void wconv(const float* __restrict__ W1,
                                             const float* __restrict__ W2,
                                             unsigned short* __restrict__ W1T,
                                             unsigned short* __restrict__ W2T) {
    int i = blockIdx.x * 256 + threadIdx.x;
    if (i >= 3 * 4096) return;
    int s = i >> 12, rem = i & 4095, c = rem >> 6, j = rem & 63;
    W1T[s * 4096 + j * 64 + c] = f2b(W1[i]);
    W2T[s * 4096 + j * 64 + c] = f2b(W2[i]);
}

// ---- all 3 scales: hash insert {key, chainhead}: 32-bit key CAS + head atomicExch ----
// Slot = int2{key, head}. After this kernel, every claimed slot has head >= 0
// (LIFO chain of point indices via next[]).
__global__ __launch_bounds__(256) void insert3(const int* __restrict__ coords,
                                               int2* __restrict__ hKV,
                                               int* __restrict__ next) {
    const int BPS = (NPTS + 255) / 256;  // 1954
    int s = blockIdx.x / BPS;
    int i = (blockIdx.x % BPS) * 256 + threadIdx.x;
    if (i >= NPTS) return;
    int shift = s + 1;
    int2* hs = hKV + (size_t)s * HSIZE;
    int4 cd = ((const int4*)coords)[i];
    int key = (((cd.w * 512 + (cd.x >> shift)) * 512 + (cd.y >> shift)) * 512 +
               (cd.z >> shift));  // < 2^27, nonnegative; -1 is safe sentinel
    unsigned h = ((unsigned)key * 2654435761u) >> 12;  // top 20 bits
    while (true) {
        int prev = atomicCAS(&hs[h].x, -1, key);
        if (prev == -1 || prev == key) break;
        h = (h + 1) & HMASK;
    }
    next[(size_t)s * NPTS + i] = atomicExch(&hs[h].y, i);
}

// ---- fused: pruned corner-argmax -> chain head; in-kernel f32 chain-walk mean;
//      3x (res@W1 -> relu*feats -> @W2 -> relu) + attention ----
// R10 lesson applied: reduce3/headfix3/vmean (183MB write + 161MB gather) deleted.
// Mean computed exactly where needed: 4 quads/row walk the voxel chain over feats
// (f32, full 256B row per step across quads). feats 128MB + hKV 24MB + next 18MB
// fit L3 -> chain reads cache-warm. Also removes bf16 vmean rounding stage.
__global__ __launch_bounds__(256, 4) void fused_mlp(const float* __restrict__ feats,
                                                    const int* __restrict__ coords,
                                                    const int2* __restrict__ hKV,
                                                    const int* __restrict__ next,
                                                    const unsigned short* __restrict__ W1T,
                                                    const unsigned short* __restrict__ W2T,
                                                    const float* __restrict__ b1,
                                                    const float* __restrict__ b2,
                                                    const float* __restrict__ Wa,
                                                    const float* __restrict__ ba,
                                                    float* __restrict__ out) {
    __shared__ __align__(16) float sF[64 * FPF];              // 17408 B
    __shared__ __align__(16) unsigned short sH[4][16 * FP];   // 9216 B
    __shared__ int sG[3][64];                                 // 768 B (chain heads)

    int tid = threadIdx.x;
    int wave = tid >> 6, lane = tid & 63;
    int ln = lane & 15, quad = lane >> 4, ko = quad * 8;
    int b0 = blockIdx.x * 64;
    int mrow = wave * 16 + ln;

    // cooperative feats tile fill: 16 floats per thread, coalesced
    int frow = tid >> 2, fcb = (tid & 3) * 16;
    {
        int n = b0 + frow;
        const float4v* src = (const float4v*)(feats + (size_t)(n < NPTS ? n : 0) * 64 + fcb);
        float4v z = {0.f, 0.f, 0.f, 0.f};
#pragma unroll
        for (int k = 0; k < 4; ++k) {
            float4v v = (n < NPTS) ? src[k] : z;
            *(float4v*)&sF[frow * FPF + fcb + 4 * k] = v;
        }
    }

    // ---- pruned argmax: thread (s,row) scans corners best-weight-first,
    //      stores the winning voxel's CHAIN HEAD ----
    if (tid < 192) {
        int row = tid & 63, s = tid >> 6;
        int n = b0 + row;
        int hd = -1;
        if (n < NPTS) {
            intx4 cd = *((const intx4*)coords + n);
            int shift = s + 1;
            const int2* hs = hKV + (size_t)s * HSIZE;
            int vx = cd.x >> shift, vy = cd.y >> shift, vz = cd.z >> shift;
            float inv = 1.0f / (float)(1 << shift);
            float fx = (float)(cd.x - (vx << shift)) * inv;  // exact dyadic
            float fy = (float)(cd.y - (vy << shift)) * inv;
            float fz = (float)(cd.z - (vz << shift)) * inv;
            float cw[8];
#pragma unroll
            for (int j = 0; j < 8; ++j) {
                float wx = ((j >> 2) & 1) ? fx : 1.0f - fx;
                float wy = ((j >> 1) & 1) ? fy : 1.0f - fy;
                float wz = (j & 1) ? fz : 1.0f - fz;
                cw[j] = (wx * wy) * wz;  // same assoc order as jnp.prod; exact f32
            }
            unsigned done = 0;
            for (int it = 0; it < 8; ++it) {
                int best = 0; float bw = -1.0f;
#pragma unroll
                for (int j = 0; j < 8; ++j)
                    if (!(done & (1u << j)) && cw[j] > bw) { bw = cw[j]; best = j; }
                int bx = (best >> 2) & 1, by = (best >> 1) & 1, bz = best & 1;
                int key = (((cd.w * 512 + (vx + bx)) * 512 + (vy + by)) * 512 + (vz + bz));
                unsigned h = ((unsigned)key * 2654435761u) >> 12;
                int hd2 = -1;
                while (true) {
                    int2 kv = hs[h];
                    if (kv.x == key) { hd2 = kv.y; break; }  // occupied -> head >= 0
                    if (kv.x == -1) break;
                    h = (h + 1) & HMASK;
                }
                if (hd2 >= 0) { hd = hd2; break; }  // first occupied in order = argmax
                done |= 1u << best;
                // terminates at latest at corner0 (always occupied, w0 > 0)
            }
        }
        sG[s][row] = hd;
    }

    __syncthreads();  // sF fill + sG ready

    float4v ms[3][4];
    unsigned short* sHw = &sH[wave][0];
    unsigned zo = 0;  // runtime-0, laundered per scale (defeats cross-scale CSE)

#pragma unroll
    for (int s = 0; s < 3; ++s) {
        asm volatile("" : "+v"(zo));

        // ---- chain-walk mean (exact f32): 4 quads of row mrow each own 16 ch ----
        float4v m0a = {0.f, 0.f, 0.f, 0.f}, m0b = {0.f, 0.f, 0.f, 0.f};
        float4v m1a = {0.f, 0.f, 0.f, 0.f}, m1b = {0.f, 0.f, 0.f, 0.f};
        int cnt = 0;
        {
            const int* nx = next + (size_t)s * NPTS;
            int i = sG[s][mrow];
            while (i >= 0) {
                const float* fr = feats + (size_t)i * 64;
                float4v p0 = *(const float4v*)&fr[ko];
                float4v p1 = *(const float4v*)&fr[ko + 4];
                float4v p2 = *(const float4v*)&fr[32 + ko];
                float4v p3 = *(const float4v*)&fr[32 + ko + 4];
                int ni = nx[i];  // independent of p*
                m0a += p0; m0b += p1; m1a += p2; m1b += p3;
                ++cnt; i = ni;
            }
        }
        float rc = 1.0f / (float)(cnt ? cnt : 1);  // cnt==0 only on OOB rows
        m0a *= rc; m0b *= rc; m1a *= rc; m1b *= rc;

        // residual A-fragments: res = feats - mean  (feats via float4 LDS reads)
        float fa0[8], fa1[8];
        *(float4v*)&fa0[0] = *(const float4v*)&sF[zo + mrow * FPF + ko];
        *(float4v*)&fa0[4] = *(const float4v*)&sF[zo + mrow * FPF + ko + 4];
        *(float4v*)&fa1[0] = *(const float4v*)&sF[zo + mrow * FPF + 32 + ko];
        *(float4v*)&fa1[4] = *(const float4v*)&sF[zo + mrow * FPF + 32 + ko + 4];
        short8 a0, a1;
#pragma unroll
        for (int j = 0; j < 4; ++j) {
            a0[j] = (short)f2b(fa0[j] - m0a[j]);
            a0[j + 4] = (short)f2b(fa0[j + 4] - m0b[j]);
            a1[j] = (short)f2b(fa1[j] - m1a[j]);
            a1[j + 4] = (short)f2b(fa1[j + 4] - m1b[j]);
        }

        // GEMM1: H = relu(res @ W1 + b1) * feats
#pragma unroll
        for (int nt = 0; nt < 4; ++nt) {
            int ncol = nt * 16 + ln;
            const unsigned short* w1r = W1T + s * 4096 + ncol * 64;
            short8 bb0 = *(const short8*)&w1r[ko];
            short8 bb1 = *(const short8*)&w1r[32 + ko];
            float4v c = {0.f, 0.f, 0.f, 0.f};
            c = __builtin_amdgcn_mfma_f32_16x16x32_bf16(a0, bb0, c, 0, 0, 0);
            c = __builtin_amdgcn_mfma_f32_16x16x32_bf16(a1, bb1, c, 0, 0, 0);
            float bias = b1[s * 64 + ncol];
#pragma unroll
            for (int r = 0; r < 4; ++r) {
                float fcv = sF[zo + (wave * 16 + quad * 4 + r) * FPF + ncol];
                float hv = fmaxf(c[r] + bias, 0.0f) * fcv;
                sHw[(quad * 4 + r) * FP + ncol] = f2b(hv);
            }
        }
        // (no fence: sH is wave-private; compiler orders aliasing LDS write->read)

        // GEMM2: ms = relu(H @ W2 + b2)
        short8 h0 = *(const short8*)&sHw[ln * FP + ko];
        short8 h1 = *(const short8*)&sHw[ln * FP + 32 + ko];
#pragma unroll
        for (int nt = 0; nt < 4; ++nt) {
            int ncol = nt * 16 + ln;
            const unsigned short* w2r = W2T + s * 4096 + ncol * 64;
            short8 bb0 = *(const short8*)&w2r[ko];
            short8 bb1 = *(const short8*)&w2r[32 + ko];
            float4v c = {0.f, 0.f, 0.f, 0.f};
            c = __builtin_amdgcn_mfma_f32_16x16x32_bf16(h0, bb0, c, 0, 0, 0);
            c = __builtin_amdgcn_mfma_f32_16x16x32_bf16(h1, bb1, c, 0, 0, 0);
            float bias2 = b2[s * 64 + ncol];
#pragma unroll
            for (int r = 0; r < 4; ++r) c[r] = fmaxf(c[r] + bias2, 0.0f);
            ms[s][nt] = c;
        }
    }

    // attention: att = sigmoid((ms0+ms1+ms2) @ Wa^T + ba); out = sum_s ms_s * att_s
    float4v sa[4];
#pragma unroll
    for (int nt = 0; nt < 4; ++nt) sa[nt] = ms[0][nt] + ms[1][nt] + ms[2][nt];
    float part[4][3];
#pragma unroll
    for (int r = 0; r < 4; ++r)
#pragma unroll
        for (int sh = 0; sh < 3; ++sh) {
            float p = 0.0f;
#pragma unroll
            for (int nt = 0; nt < 4; ++nt) p += sa[nt][r] * Wa[sh * 64 + nt * 16 + ln];
            part[r][sh] = p;
        }
    for (int m = 1; m < 16; m <<= 1)
#pragma unroll
        for (int r = 0; r < 4; ++r)
#pragma unroll
            for (int sh = 0; sh < 3; ++sh) part[r][sh] += __shfl_xor(part[r][sh], m);
    float att[4][3];
#pragma unroll
    for (int r = 0; r < 4; ++r)
#pragma unroll
        for (int sh = 0; sh < 3; ++sh)
            att[r][sh] = 1.0f / (1.0f + expf(-(part[r][sh] + ba[sh])));

#pragma unroll
    for (int nt = 0; nt < 4; ++nt)
#pragma unroll
        for (int r = 0; r < 4; ++r) {
            int n = b0 + wave * 16 + quad * 4 + r;
            if (n < NPTS) {
                float o = ms[0][nt][r] * att[r][0] + ms[1][nt][r] * att[r][1] +
                          ms[2][nt][r] * att[r][2];
                out[(size_t)n * 64 + nt * 16 + ln] = o;
            }
        }
}

extern "C" void kernel_launch(void* const* d_in, const int* in_sizes, int n_in,
                              void* d_out, int out_size, void* d_ws, size_t ws_size,
                              hipStream_t stream) {
    const float* feats = (const float*)d_in[0];
    const int* coords = (const int*)d_in[1];
    const float* W1 = (const float*)d_in[2];
    const float* b1 = (const float*)d_in[3];
    const float* W2 = (const float*)d_in[4];
    const float* b2 = (const float*)d_in[5];
    const float* Wa = (const float*)d_in[6];
    const float* ba = (const float*)d_in[7];
    float* out = (float*)d_out;

    char* ws = (char*)d_ws;
    size_t o = 0;
    unsigned short* W1T = (unsigned short*)(ws + o); o += 3 * 4096 * 2;
    unsigned short* W2T = (unsigned short*)(ws + o); o += 3 * 4096 * 2;
    o = (o + 255) & ~(size_t)255;
    int* next = (int*)(ws + o); o += (size_t)3 * NPTS * 4;
    o = (o + 255) & ~(size_t)255;
    int2* hKV = (int2*)(ws + o); o += (size_t)3 * HSIZE * 8;
    // total ~30 MB

    wconv<<<48, 256, 0, stream>>>(W1, W2, W1T, W2T);
    (void)hipMemsetAsync(hKV, 0xFF, (size_t)3 * HSIZE * 8, stream);  // key=-1, head=-1

    const int BPS = (NPTS + 255) / 256;
    insert3<<<3 * BPS, 256, 0, stream>>>(coords, hKV, next);
    fused_mlp<<<(NPTS + 63) / 64, 256, 0, stream>>>(feats, coords, hKV, next,
                                                    W1T, W2T, b1, b2, Wa, ba, out);
}